// Round 7
// baseline (6423.926 us; speedup 1.0000x reference)
//
#include <hip/hip_runtime.h>
#include <hip/hip_fp16.h>

#define TT   2048
#define EMBD 256
#define HD   256      // H2
#define NG   1024     // 4*H2
#define NC   12
#define NEGV -10000.0f

#define NRESD 28      // resident weight dwords per (row, K-quarter); 4 more in LDS

typedef _Float16 half2v __attribute__((ext_vector_type(2)));

// ---- static device scratch (zero dependence on d_ws) ----
__device__ float g_P[2 * TT * NG];   // input-GEMM preactivations (16 MB)
__device__ float g_HS[2 * TT * HD];  // hidden states both dirs (4 MB)
__device__ float g_FE[TT * NC];      // CRF emission feats (96 KB)

// pack two f32 -> two f16 in one dword (round-to-nearest each)
__device__ __forceinline__ unsigned int f2h2(float a, float b) {
  half2v h; h.x = (_Float16)a; h.y = (_Float16)b;
  return __builtin_bit_cast(unsigned int, h);
}
// acc += w2.x*h2.x + w2.y*h2.y   (v_dot2_f32_f16: f32 accumulate)
__device__ __forceinline__ float fdot2(unsigned int w2, unsigned int h2, float acc) {
  return __builtin_amdgcn_fdot2(__builtin_bit_cast(half2v, w2),
                                __builtin_bit_cast(half2v, h2), acc, false);
}
__device__ __forceinline__ float fsigmoid(float x) { return 1.0f / (1.0f + __expf(-x)); }
__device__ __forceinline__ float ftanh(float x) {
  float a = fabsf(x);
  float e = __expf(-2.0f * a);
  float r = (1.0f - e) / (1.0f + e);
  return copysignf(r, x);
}

// ---------------- K1: embedding gather + input GEMM (+ both biases), all f32 ----------------
__global__ __launch_bounds__(256) void k_input(
    const int* __restrict__ sent, const float* __restrict__ emb,
    const float* __restrict__ WihF, const float* __restrict__ bihF,
    const float* __restrict__ bhhF,
    const float* __restrict__ WihB, const float* __restrict__ bihB,
    const float* __restrict__ bhhB)
{
  const int d  = blockIdx.x & 1;
  const int t0 = (blockIdx.x >> 1) * 16;
  const float* Wih = d ? WihB : WihF;
  const float* bih = d ? bihB : bihF;
  const float* bhh = d ? bhhB : bhhF;
  __shared__ float xs[16][EMBD];
  for (int i = threadIdx.x; i < 16 * (EMBD / 4); i += 256) {
    const int tt = i >> 6, e4 = i & 63;
    reinterpret_cast<float4*>(xs[tt])[e4] =
        reinterpret_cast<const float4*>(emb + (size_t)sent[t0 + tt] * EMBD)[e4];
  }
  __syncthreads();
  for (int gg = 0; gg < 4; ++gg) {
    const int g = threadIdx.x + gg * 256;
    const float bias = bih[g] + bhh[g];
    float acc[16];
#pragma unroll
    for (int tt = 0; tt < 16; ++tt) acc[tt] = 0.0f;
    const float* wr = Wih + (size_t)g * EMBD;
    for (int e = 0; e < EMBD; e += 4) {
      const float4 w = *reinterpret_cast<const float4*>(wr + e);
#pragma unroll
      for (int tt = 0; tt < 16; ++tt) {
        acc[tt] += w.x * xs[tt][e] + w.y * xs[tt][e + 1]
                 + w.z * xs[tt][e + 2] + w.w * xs[tt][e + 3];
      }
    }
    float* Pg = g_P + ((size_t)d * TT + t0) * NG + g;
#pragma unroll
    for (int tt = 0; tt < 16; ++tt) Pg[(size_t)tt * NG] = acc[tt] + bias;
  }
}

// ---------------- K2: BiLSTM recurrence — K-quartered, 8 rows/thread ----------------
// 512 thr/block, 1 block/dir. lane[3:0]+wave -> row-group rg (units 2rg,2rg+1);
// lane[5:4] = q -> K-slice [64q,64q+64). Per thread: 8 rows x 64-K dots, partials
// combined via shfl_xor(16/32). q==0 lanes do the gate epilogue for 2 units
// (thread-local c!) and write h (f16x2) + HS. One barrier per step.
__global__ __launch_bounds__(512, 2) void k_rec(
    const float* __restrict__ WhhF, const float* __restrict__ WhhB,
    const float* __restrict__ h0g, const float* __restrict__ c0g)
{
  __shared__ __align__(16) unsigned int h2[2][HD / 2];  // f16x2 h, double-buffered
  __shared__ uint4 wt4[8][8][64];                       // 64 KB tail weights, per-thread slot

  const int d = blockIdx.x;
  const float* Whh = d ? WhhB : WhhF;
  const int tid  = threadIdx.x;
  const int wave = tid >> 6;
  const int lane = tid & 63;
  const int l4   = lane & 15;
  const int q    = lane >> 4;          // K-quarter
  const int rg   = wave * 16 + l4;     // row-group 0..127
  const int u0   = 2 * rg;             // units u0, u0+1

  // ---- init: pack weights f32 -> f16x2; rows r = gate*2 + unitsel ----
  unsigned int w[8][NRESD];
#pragma unroll
  for (int r = 0; r < 8; ++r) {
    const float* wr = Whh + (size_t)((r >> 1) * 256 + u0 + (r & 1)) * HD + q * 64;
#pragma unroll
    for (int e = 0; e < NRESD; ++e) {
      const float2 a = *reinterpret_cast<const float2*>(wr + 2 * e);
      w[r][e] = f2h2(a.x, a.y);
    }
    uint4 tw;
    tw.x = f2h2(wr[56], wr[57]);
    tw.y = f2h2(wr[58], wr[59]);
    tw.z = f2h2(wr[60], wr[61]);
    tw.w = f2h2(wr[62], wr[63]);
    wt4[r][wave][lane] = tw;           // read back by the same thread: lane-contiguous b128
  }
  if (tid < HD / 2)
    h2[0][tid] = f2h2(h0g[d * HD + 2 * tid], h0g[d * HD + 2 * tid + 1]);
  float c0v = 0.f, c1v = 0.f;
  if (q == 0) {
    c0v = c0g[d * HD + u0];
    c1v = c0g[d * HD + u0 + 1];
  }
  __syncthreads();

  int t = d ? (TT - 1) : 0;
  const int ts = d ? -1 : 1;
  for (int it = 0; it < TT; ++it, t += ts) {
    float2 pi, pf, pg, po;
    if (q == 0) {                      // issued early, consumed after the dot loop
      const float* Pt = g_P + ((size_t)d * TT + t) * NG;
      pi = *reinterpret_cast<const float2*>(Pt + u0);
      pf = *reinterpret_cast<const float2*>(Pt + 256 + u0);
      pg = *reinterpret_cast<const float2*>(Pt + 512 + u0);
      po = *reinterpret_cast<const float2*>(Pt + 768 + u0);
    }
    const unsigned int* hc = h2[it & 1] + q * 32;
    float acc[8] = {0.f, 0.f, 0.f, 0.f, 0.f, 0.f, 0.f, 0.f};
#pragma unroll
    for (int jb = 0; jb < 7; ++jb) {   // resident dwords 0..27
      const uint4 hv = *reinterpret_cast<const uint4*>(hc + 4 * jb);
#pragma unroll
      for (int r = 0; r < 8; ++r) {
        acc[r] = fdot2(w[r][4 * jb + 0], hv.x, acc[r]);
        acc[r] = fdot2(w[r][4 * jb + 1], hv.y, acc[r]);
        acc[r] = fdot2(w[r][4 * jb + 2], hv.z, acc[r]);
        acc[r] = fdot2(w[r][4 * jb + 3], hv.w, acc[r]);
      }
    }
    {                                  // LDS tail: dwords 28..31
      const uint4 hv = *reinterpret_cast<const uint4*>(hc + 28);
#pragma unroll
      for (int r = 0; r < 8; ++r) {
        const uint4 tw = wt4[r][wave][lane];
        acc[r] = fdot2(tw.x, hv.x, acc[r]);
        acc[r] = fdot2(tw.y, hv.y, acc[r]);
        acc[r] = fdot2(tw.z, hv.z, acc[r]);
        acc[r] = fdot2(tw.w, hv.w, acc[r]);
      }
    }
    // combine the 4 K-quarter partials (lanes differing in bits 4,5)
#pragma unroll
    for (int r = 0; r < 8; ++r) {
      acc[r] += __shfl_xor(acc[r], 16);
      acc[r] += __shfl_xor(acc[r], 32);
    }
    if (q == 0) {
      const float gi0 = acc[0] + pi.x, gi1 = acc[1] + pi.y;
      const float gf0 = acc[2] + pf.x, gf1 = acc[3] + pf.y;
      const float gg0 = acc[4] + pg.x, gg1 = acc[5] + pg.y;
      const float go0 = acc[6] + po.x, go1 = acc[7] + po.y;
      c0v = fsigmoid(gf0) * c0v + fsigmoid(gi0) * ftanh(gg0);
      c1v = fsigmoid(gf1) * c1v + fsigmoid(gi1) * ftanh(gg1);
      const float h0v = fsigmoid(go0) * ftanh(c0v);
      const float h1v = fsigmoid(go1) * ftanh(c1v);
      *reinterpret_cast<float2*>(g_HS + ((size_t)d * TT + t) * HD + u0) =
          make_float2(h0v, h1v);
      h2[(it & 1) ^ 1][rg] = f2h2(h0v, h1v);
    }
    __syncthreads();
  }
}

// ---------------- K3: feats = [hf;hb] @ Wlin^T + blin (pure f32) ----------------
__global__ __launch_bounds__(256) void k_feats(
    const float* __restrict__ Wlin, const float* __restrict__ blin)
{
  const int gid = blockIdx.x * 256 + threadIdx.x;
  if (gid >= TT * NC) return;
  const int t = gid / NC, cc = gid - t * NC;
  const float* hf = g_HS + (size_t)t * HD;
  const float* hb = g_HS + ((size_t)TT + t) * HD;
  const float* wr = Wlin + cc * 512;
  float acc = blin[cc];
  for (int j = 0; j < HD; j += 4) {
    const float4 w = *reinterpret_cast<const float4*>(wr + j);
    acc += w.x * hf[j] + w.y * hf[j + 1] + w.z * hf[j + 2] + w.w * hf[j + 3];
  }
  for (int j = 0; j < HD; j += 4) {
    const float4 w = *reinterpret_cast<const float4*>(wr + 256 + j);
    acc += w.x * hb[j] + w.y * hb[j + 1] + w.z * hb[j + 2] + w.w * hb[j + 3];
  }
  g_FE[gid] = acc;
}

// ---------------- K4: Viterbi + backtrace (single wave); f32 in/out ----------------
__global__ __launch_bounds__(64) void k_vit(
    const float* __restrict__ trans, float* __restrict__ out)
{
  const int lane = threadIdx.x;
  const bool act = lane < NC;
  __shared__ unsigned char bp[TT][NC];
  float Trow[NC];
#pragma unroll
  for (int i = 0; i < NC; ++i) Trow[i] = act ? trans[lane * NC + i] : NEGV;
  float fv[NC];
#pragma unroll
  for (int i = 0; i < NC; ++i) fv[i] = (i == 10) ? 0.0f : NEGV;  // START=10

  float f0 = act ? g_FE[lane] : 0.0f;                 // 2-deep FE prefetch
  float f1 = act ? g_FE[NC + lane] : 0.0f;
  for (int t = 0; t < TT; ++t) {
    const float feat = f0;
    f0 = f1;
    f1 = (act && t + 2 < TT) ? g_FE[(t + 2) * NC + lane] : 0.0f;
    float best = fv[0] + Trow[0]; int bi = 0;
#pragma unroll
    for (int i = 1; i < NC; ++i) {
      const float s = fv[i] + Trow[i];
      if (s > best) { best = s; bi = i; }   // strict > == jnp first-max tiebreak
    }
    if (act) bp[t][lane] = (unsigned char)bi;
    const float nf = best + feat;
#pragma unroll
    for (int i = 0; i < NC; ++i) fv[i] = __shfl(nf, i);
  }
  // terminal = fv + transitions[STOP=11] (row 11)
  const float term = act ? (fv[lane] + trans[11 * NC + lane]) : -3.0e38f;
  float tv[NC];
#pragma unroll
  for (int i = 0; i < NC; ++i) tv[i] = __shfl(term, i);
  if (lane == 0) {
    float bs = tv[0]; int bt = 0;
#pragma unroll
    for (int i = 1; i < NC; ++i) if (tv[i] > bs) { bs = tv[i]; bt = i; }
    out[0] = bs;                             // f32 path_score
    int tag = bt;
    for (int t = TT - 1; t >= 0; --t) {
      out[1 + t] = (float)tag;               // path tags as f32
      tag = bp[t][tag];
    }
  }
}

extern "C" void kernel_launch(void* const* d_in, const int* in_sizes, int n_in,
                              void* d_out, int out_size, void* d_ws, size_t ws_size,
                              hipStream_t stream) {
  const int*   sent = (const int*)d_in[0];
  const float* emb  = (const float*)d_in[1];
  const float* WihF = (const float*)d_in[2];
  const float* WhhF = (const float*)d_in[3];
  const float* bihF = (const float*)d_in[4];
  const float* bhhF = (const float*)d_in[5];
  const float* WihB = (const float*)d_in[6];
  const float* WhhB = (const float*)d_in[7];
  const float* bihB = (const float*)d_in[8];
  const float* bhhB = (const float*)d_in[9];
  const float* Wlin = (const float*)d_in[10];
  const float* blin = (const float*)d_in[11];
  const float* h0g  = (const float*)d_in[12];
  const float* c0g  = (const float*)d_in[13];
  const float* trans= (const float*)d_in[14];
  (void)d_ws; (void)ws_size; (void)in_sizes; (void)n_in; (void)out_size;

  k_input<<<dim3(2 * (TT / 16)), dim3(256), 0, stream>>>(
      sent, emb, WihF, bihF, bhhF, WihB, bihB, bhhB);

  k_rec<<<dim3(2), dim3(512), 0, stream>>>(WhhF, WhhB, h0g, c0g);

  k_feats<<<dim3((TT * NC + 255) / 256), dim3(256), 0, stream>>>(Wlin, blin);

  k_vit<<<dim3(1), dim3(64), 0, stream>>>(trans, (float*)d_out);
}